// Round 6
// baseline (162.814 us; speedup 1.0000x reference)
//
#include <hip/hip_runtime.h>

#define D 32
#define EPS 1e-5f
#define TPB 256
#define NB 256              // blocks for the etype counting-sort passes
#define RNB_MAX 25600       // R*NB upper bound staged in LDS (R<=100)
#define SCAN_T 1024

// ---------------- E1: per-block etype histogram + global dst histogram ----
__global__ void histE_kernel(const int* __restrict__ etype, const int* __restrict__ dst,
                             int E, int R, int chunk,
                             int* __restrict__ blockHistT,   // [R][NB]
                             int* __restrict__ nodeCnt)
{
    __shared__ int lh[1024];
    for (int i = threadIdx.x; i < R; i += TPB) lh[i] = 0;
    __syncthreads();
    const int lo = blockIdx.x * chunk, hi = min(E, lo + chunk);
    for (int e = lo + threadIdx.x; e < hi; e += TPB) {
        atomicAdd(&lh[etype[e]], 1);
        atomicAdd(&nodeCnt[dst[e]], 1);   // fire-and-forget, 20000 bins
    }
    __syncthreads();
    for (int r = threadIdx.x; r < R; r += TPB)
        blockHistT[r * NB + blockIdx.x] = lh[r];
}

// ---------------- S: ONE merged scan kernel --------------------------------
// Phase A: flat exclusive scan of blockHistT[R*NB] (relation-major) -> the
//   absolute scatter base for (r, block). rel_start[r] = scan[r*NB]. Builds
//   the per-256-edge task list.
// Phase B (LDS buffer reused): exclusive scan of nodeCnt -> node_start/curD.
__global__ __launch_bounds__(SCAN_T)
void scanAll_kernel(int* __restrict__ blockHistT, int R,
                    const int* __restrict__ nodeCnt, int N, int E,
                    int* __restrict__ rel_start,
                    int* __restrict__ task_rel, int* __restrict__ task_start,
                    int* __restrict__ n_tasks,
                    int* __restrict__ node_start, int* __restrict__ curD)
{
    __shared__ int s_buf[RNB_MAX];
    __shared__ int s_part[SCAN_T];
    __shared__ int s_tbase[1024];
    const int t = threadIdx.x;

    // ---- Phase A: flat scan over M = R*NB ----
    const int M = R * NB;
    for (int i = t; i < M; i += SCAN_T) s_buf[i] = blockHistT[i];
    __syncthreads();
    {
        const int per = (M + SCAN_T - 1) / SCAN_T;
        const int lo = min(t * per, M), hi = min(lo + per, M);
        int s = 0;
        for (int i = lo; i < hi; ++i) s += s_buf[i];
        s_part[t] = s;
        __syncthreads();
        int x = s;
        for (int off = 1; off < SCAN_T; off <<= 1) {
            const int y = (t >= off) ? s_part[t - off] : 0;
            __syncthreads();
            x += y;
            s_part[t] = x;
            __syncthreads();
        }
        int run = x - s;
        for (int i = lo; i < hi; ++i) { const int v = s_buf[i]; s_buf[i] = run; run += v; }
    }
    __syncthreads();
    for (int i = t; i < M; i += SCAN_T) blockHistT[i] = s_buf[i];
    for (int r = t; r < R; r += SCAN_T) rel_start[r] = s_buf[r * NB];
    if (t == 0) rel_start[R] = E;
    // task list: totals per relation, serial base accumulation (R small)
    if (t == 0) {
        int tb = 0;
        for (int r = 0; r < R; ++r) {
            const int st  = s_buf[r * NB];
            const int en  = (r + 1 < R) ? s_buf[(r + 1) * NB] : E;
            s_tbase[r] = tb;
            tb += (en - st + TPB - 1) / TPB;
        }
        *n_tasks = tb;
    }
    __syncthreads();
    if (t < R) {
        const int st = s_buf[t * NB];
        const int en = (t + 1 < R) ? s_buf[(t + 1) * NB] : E;
        const int nb = (en - st + TPB - 1) / TPB;
        const int tb = s_tbase[t];
        for (int b = 0; b < nb; ++b) {
            task_rel[tb + b]   = t;
            task_start[tb + b] = st + b * TPB;
        }
    }
    __syncthreads();

    // ---- Phase B: node-count scan (reuse s_buf) ----
    for (int i = t; i < N; i += SCAN_T) s_buf[i] = nodeCnt[i];
    __syncthreads();
    {
        const int per = (N + SCAN_T - 1) / SCAN_T;
        const int lo = min(t * per, N), hi = min(lo + per, N);
        int s = 0;
        for (int i = lo; i < hi; ++i) s += s_buf[i];
        s_part[t] = s;
        __syncthreads();
        int x = s;
        for (int off = 1; off < SCAN_T; off <<= 1) {
            const int y = (t >= off) ? s_part[t - off] : 0;
            __syncthreads();
            x += y;
            s_part[t] = x;
            __syncthreads();
        }
        int run = x - s;
        for (int i = lo; i < hi; ++i) { const int v = s_buf[i]; s_buf[i] = run; run += v; }
    }
    __syncthreads();
    for (int i = t; i < N; i += SCAN_T) {
        const int v = s_buf[i];
        node_start[i] = v;
        curD[i] = v;
    }
    if (t == 0) node_start[N] = E;
}

// ---------------- E3: scatter into etype-sorted order ---------------------
__global__ void scatterE_kernel(const int* __restrict__ src, const int* __restrict__ dst,
                                const int* __restrict__ etype, int E, int R, int chunk,
                                const int* __restrict__ blockHistT,  // absolute bases now
                                int* __restrict__ ssrc, int* __restrict__ sdst)
{
    __shared__ int cur[1024];
    for (int r = threadIdx.x; r < R; r += TPB)
        cur[r] = blockHistT[r * NB + blockIdx.x];
    __syncthreads();
    const int lo = blockIdx.x * chunk, hi = min(E, lo + chunk);
    for (int e = lo + threadIdx.x; e < hi; e += TPB) {
        const int p = atomicAdd(&cur[etype[e]], 1);   // LDS atomic only
        ssrc[p] = src[e];
        sdst[p] = dst[e];
    }
}

// ---------------- C: compute msg = relu(h[src] @ W[r]) + perm placement ---
__global__ __launch_bounds__(TPB)
void rgcn_compute(const float* __restrict__ h, const float* __restrict__ W,
                  const int* __restrict__ rel_start,
                  const int* __restrict__ task_rel, const int* __restrict__ task_start,
                  const int* __restrict__ n_tasks_p,
                  const int* __restrict__ ssrc, const int* __restrict__ sdst,
                  int* __restrict__ curD, int* __restrict__ perm,
                  float* __restrict__ msg,
                  float* __restrict__ stat_sum, float* __restrict__ stat_sq)
{
    __shared__ float s_tile[TPB * 33];
    __shared__ int   s_src[TPB];
    __shared__ float s_aux[2 * TPB];

    const int task = blockIdx.x;
    if (task >= *n_tasks_p) return;
    const int r      = task_rel[task];
    const int start  = task_start[task];
    const int relEnd = rel_start[r + 1];
    const int nE     = min(TPB, relEnd - start);
    const int tid    = threadIdx.x;

    if (tid < nE) {
        s_src[tid] = ssrc[start + tid];
        const int p = atomicAdd(&curD[sdst[start + tid]], 1);
        perm[p] = start + tid;
    }
    __syncthreads();

    for (int i = tid; i < nE * 8; i += TPB) {
        const int row = i >> 3, seg = i & 7;
        const float4 v = *(const float4*)(h + (size_t)s_src[row] * D + seg * 4);
        float* p = &s_tile[row * 33 + seg * 4];
        p[0] = v.x; p[1] = v.y; p[2] = v.z; p[3] = v.w;
    }
    __syncthreads();

    const float* Wr = W + (size_t)__builtin_amdgcn_readfirstlane(r) * (D * D);

    float acc[D];
#pragma unroll
    for (int o = 0; o < D; ++o) acc[o] = 0.f;

    if (tid < nE) {
#pragma unroll 4
        for (int d = 0; d < D; ++d) {
            const float hd = s_tile[tid * 33 + d];
#pragma unroll
            for (int o = 0; o < D; ++o)
                acc[o] = fmaf(hd, Wr[d * D + o], acc[o]);
        }
#pragma unroll
        for (int o = 0; o < D; ++o) acc[o] = fmaxf(acc[o], 0.f);
    }
    __syncthreads();

    if (tid < nE) {
#pragma unroll
        for (int o = 0; o < D; ++o) s_tile[tid * 33 + o] = acc[o];
    }
    __syncthreads();

    float ps = 0.f, pq = 0.f;
    float* mbase = msg + (size_t)start * D;
    for (int i = tid; i < nE * D; i += TPB) {
        const int row = i >> 5, o = i & 31;
        const float v = s_tile[row * 33 + o];
        mbase[i] = v;
        ps += v; pq += v * v;
    }
    s_aux[tid]       = ps;
    s_aux[TPB + tid] = pq;
    __syncthreads();
    if (tid < D) {
        float ss = 0.f, sq = 0.f;
#pragma unroll
        for (int c = 0; c < TPB / D; ++c) {
            ss += s_aux[c * D + tid];
            sq += s_aux[TPB + c * D + tid];
        }
        atomicAdd(&stat_sum[tid], ss);
        atomicAdd(&stat_sq[tid],  sq);
    }
}

// ---------------- R: per-node gather-reduce + BN fold + mean --------------
// 32 lanes per node. perm indices pre-loaded in one coalesced shot, then
// shfl-broadcast -> msg row loads are independent (batch-issuable).
__global__ void reduce_kernel(const float* __restrict__ msg, const int* __restrict__ perm,
                              const int* __restrict__ node_start,
                              const float* __restrict__ stat_sum,
                              const float* __restrict__ stat_sq,
                              const float* __restrict__ gamma,
                              const float* __restrict__ beta,
                              float invE, float* __restrict__ out, int N)
{
    const int o = threadIdx.x & 31;
    const int n = blockIdx.x * 8 + (threadIdx.x >> 5);
    if (n >= N) return;
    const int j0 = node_start[n], j1 = node_start[n + 1];
    float s = 0.f;
    for (int base = j0; base < j1; base += 32) {
        const int cnt = min(32, j1 - base);
        const int myj = (o < cnt) ? perm[base + o] : 0;
#pragma unroll 8
        for (int k = 0; k < cnt; ++k) {
            const int e = __shfl(myj, k, 32);
            s += msg[(size_t)e * D + o];
        }
    }
    const float mu  = stat_sum[o] * invE;
    const float var = fmaxf(stat_sq[o] * invE - mu * mu, 0.f);
    const float is  = rsqrtf(var + EPS);
    const float sc  = gamma[o] * is;
    const float sh  = fmaf(-mu, sc, beta[o]);
    const float c   = (float)(j1 - j0);
    out[(size_t)n * D + o] = fmaf(s, sc, sh * c) / fmaxf(c, 1.0f);
}

extern "C" void kernel_launch(void* const* d_in, const int* in_sizes, int n_in,
                              void* d_out, int out_size, void* d_ws, size_t ws_size,
                              hipStream_t stream)
{
    const float* h     = (const float*)d_in[0];
    const float* W     = (const float*)d_in[1];
    const float* gamma = (const float*)d_in[2];
    const float* beta  = (const float*)d_in[3];
    const int*   src   = (const int*)d_in[4];
    const int*   dst   = (const int*)d_in[5];
    const int*   etype = (const int*)d_in[6];
    float* out = (float*)d_out;

    const int E = in_sizes[4];
    const int N = in_sizes[0] / D;
    const int R = in_sizes[1] / (D * D);
    const int T = R + (E + TPB - 1) / TPB;        // max task count
    const int chunk = (E + NB - 1) / NB;

    // ws layout (4B words):
    // [zeroed: nodeCnt N | stat_sum 32 | stat_sq 32]
    // [node_start N+1 | curD N | rel_start R+1 | n_tasks 1 |
    //  blockHistT R*NB | task_rel T | task_start T | ssrc E | sdst E | perm E |
    //  msg E*D]
    int*   nodeCnt   = (int*)d_ws;
    float* stat_sum  = (float*)(nodeCnt + N);
    float* stat_sq   = stat_sum + D;
    int*   node_start= (int*)(stat_sq + D);
    int*   curD      = node_start + N + 1;
    int*   rel_start = curD + N;
    int*   n_tasks   = rel_start + R + 1;
    int*   blockHistT= n_tasks + 1;
    int*   task_rel  = blockHistT + R * NB;
    int*   task_start= task_rel + T;
    int*   ssrc      = task_start + T;
    int*   sdst      = ssrc + E;
    int*   perm      = sdst + E;
    float* msg       = (float*)(perm + E);

    hipMemsetAsync(d_ws, 0, sizeof(int) * (size_t)(N + 2 * D), stream);

    histE_kernel<<<NB, TPB, 0, stream>>>(etype, dst, E, R, chunk, blockHistT, nodeCnt);
    scanAll_kernel<<<1, SCAN_T, 0, stream>>>(blockHistT, R, nodeCnt, N, E,
                                             rel_start, task_rel, task_start, n_tasks,
                                             node_start, curD);
    scatterE_kernel<<<NB, TPB, 0, stream>>>(src, dst, etype, E, R, chunk,
                                            blockHistT, ssrc, sdst);
    rgcn_compute<<<T, TPB, 0, stream>>>(h, W, rel_start, task_rel, task_start,
                                        n_tasks, ssrc, sdst, curD, perm,
                                        msg, stat_sum, stat_sq);
    reduce_kernel<<<(N + 7) / 8, TPB, 0, stream>>>(msg, perm, node_start,
                                                   stat_sum, stat_sq, gamma, beta,
                                                   1.0f / (float)E, out, N);
}

// Round 7
// 156.249 us; speedup vs baseline: 1.0420x; 1.0420x over previous
//
#include <hip/hip_runtime.h>

#define D 32
#define EPS 1e-5f
#define TPB 256
#define NB 256              // blocks for the etype counting-sort passes
#define RNB_MAX 25600       // R*NB upper bound staged in LDS (R<=100)
#define SCAN_T 1024

// ---------------- E1: per-block etype histogram + global dst histogram ----
__global__ void histE_kernel(const int* __restrict__ etype, const int* __restrict__ dst,
                             int E, int R, int chunk,
                             int* __restrict__ blockHistT,   // [R][NB]
                             int* __restrict__ nodeCnt)
{
    __shared__ int lh[1024];
    for (int i = threadIdx.x; i < R; i += TPB) lh[i] = 0;
    __syncthreads();
    const int lo = blockIdx.x * chunk, hi = min(E, lo + chunk);
    for (int e = lo + threadIdx.x; e < hi; e += TPB) {
        atomicAdd(&lh[etype[e]], 1);
        atomicAdd(&nodeCnt[dst[e]], 1);   // fire-and-forget, 20000 bins
    }
    __syncthreads();
    for (int r = threadIdx.x; r < R; r += TPB)
        blockHistT[r * NB + blockIdx.x] = lh[r];
}

// ---------------- S: merged scan kernel ------------------------------------
// Phase A: flat exclusive scan of blockHistT[R*NB] -> absolute scatter bases;
//   rel_start + per-256-edge task list.
// Phase B: exclusive scan of nodeCnt -> node_start / curD.
__global__ __launch_bounds__(SCAN_T)
void scanAll_kernel(int* __restrict__ blockHistT, int R,
                    const int* __restrict__ nodeCnt, int N, int E,
                    int* __restrict__ rel_start,
                    int* __restrict__ task_rel, int* __restrict__ task_start,
                    int* __restrict__ n_tasks,
                    int* __restrict__ node_start, int* __restrict__ curD)
{
    __shared__ int s_buf[RNB_MAX];
    __shared__ int s_part[SCAN_T];
    __shared__ int s_tbase[1024];
    const int t = threadIdx.x;

    // ---- Phase A ----
    const int M = R * NB;
    for (int i = t; i < M; i += SCAN_T) s_buf[i] = blockHistT[i];
    __syncthreads();
    {
        const int per = (M + SCAN_T - 1) / SCAN_T;
        const int lo = min(t * per, M), hi = min(lo + per, M);
        int s = 0;
        for (int i = lo; i < hi; ++i) s += s_buf[i];
        s_part[t] = s;
        __syncthreads();
        int x = s;
        for (int off = 1; off < SCAN_T; off <<= 1) {
            const int y = (t >= off) ? s_part[t - off] : 0;
            __syncthreads();
            x += y;
            s_part[t] = x;
            __syncthreads();
        }
        int run = x - s;
        for (int i = lo; i < hi; ++i) { const int v = s_buf[i]; s_buf[i] = run; run += v; }
    }
    __syncthreads();
    for (int i = t; i < M; i += SCAN_T) blockHistT[i] = s_buf[i];
    for (int r = t; r < R; r += SCAN_T) rel_start[r] = s_buf[r * NB];
    if (t == 0) rel_start[R] = E;
    if (t == 0) {
        int tb = 0;
        for (int r = 0; r < R; ++r) {
            const int st  = s_buf[r * NB];
            const int en  = (r + 1 < R) ? s_buf[(r + 1) * NB] : E;
            s_tbase[r] = tb;
            tb += (en - st + TPB - 1) / TPB;
        }
        *n_tasks = tb;
    }
    __syncthreads();
    if (t < R) {
        const int st = s_buf[t * NB];
        const int en = (t + 1 < R) ? s_buf[(t + 1) * NB] : E;
        const int nb = (en - st + TPB - 1) / TPB;
        const int tb = s_tbase[t];
        for (int b = 0; b < nb; ++b) {
            task_rel[tb + b]   = t;
            task_start[tb + b] = st + b * TPB;
        }
    }
    __syncthreads();

    // ---- Phase B ----
    for (int i = t; i < N; i += SCAN_T) s_buf[i] = nodeCnt[i];
    __syncthreads();
    {
        const int per = (N + SCAN_T - 1) / SCAN_T;
        const int lo = min(t * per, N), hi = min(lo + per, N);
        int s = 0;
        for (int i = lo; i < hi; ++i) s += s_buf[i];
        s_part[t] = s;
        __syncthreads();
        int x = s;
        for (int off = 1; off < SCAN_T; off <<= 1) {
            const int y = (t >= off) ? s_part[t - off] : 0;
            __syncthreads();
            x += y;
            s_part[t] = x;
            __syncthreads();
        }
        int run = x - s;
        for (int i = lo; i < hi; ++i) { const int v = s_buf[i]; s_buf[i] = run; run += v; }
    }
    __syncthreads();
    for (int i = t; i < N; i += SCAN_T) {
        const int v = s_buf[i];
        node_start[i] = v;
        curD[i] = v;
    }
    if (t == 0) node_start[N] = E;
}

// ---------------- E3: scatter into etype-sorted order ---------------------
__global__ void scatterE_kernel(const int* __restrict__ src, const int* __restrict__ dst,
                                const int* __restrict__ etype, int E, int R, int chunk,
                                const int* __restrict__ blockHistT,  // absolute bases
                                int* __restrict__ ssrc, int* __restrict__ sdst)
{
    __shared__ int cur[1024];
    for (int r = threadIdx.x; r < R; r += TPB)
        cur[r] = blockHistT[r * NB + blockIdx.x];
    __syncthreads();
    const int lo = blockIdx.x * chunk, hi = min(E, lo + chunk);
    for (int e = lo + threadIdx.x; e < hi; e += TPB) {
        const int p = atomicAdd(&cur[etype[e]], 1);   // LDS atomic only
        ssrc[p] = src[e];
        sdst[p] = dst[e];
    }
}

// ---------------- C: compute msg = relu(h[src] @ W[r]), store DST-SORTED --
// One block = up to 256 edges of ONE relation. Each edge's dst-run slot p is
// claimed up front (latency hidden by the matmul); the message row is written
// directly to msg[p*D] so the reduce pass reads msg purely sequentially.
__global__ __launch_bounds__(TPB)
void rgcn_compute(const float* __restrict__ h, const float* __restrict__ W,
                  const int* __restrict__ rel_start,
                  const int* __restrict__ task_rel, const int* __restrict__ task_start,
                  const int* __restrict__ n_tasks_p,
                  const int* __restrict__ ssrc, const int* __restrict__ sdst,
                  int* __restrict__ curD,
                  float* __restrict__ msg,
                  float* __restrict__ stat_sum, float* __restrict__ stat_sq)
{
    __shared__ float s_tile[TPB * 33];
    __shared__ int   s_src[TPB];
    __shared__ int   s_pos[TPB];
    __shared__ float s_aux[2 * TPB];

    const int task = blockIdx.x;
    if (task >= *n_tasks_p) return;
    const int r      = task_rel[task];
    const int start  = task_start[task];
    const int relEnd = rel_start[r + 1];
    const int nE     = min(TPB, relEnd - start);
    const int tid    = threadIdx.x;

    if (tid < nE) {
        s_src[tid] = ssrc[start + tid];
        s_pos[tid] = atomicAdd(&curD[sdst[start + tid]], 1);  // dst-run slot
    }
    __syncthreads();

    for (int i = tid; i < nE * 8; i += TPB) {
        const int row = i >> 3, seg = i & 7;
        const float4 v = *(const float4*)(h + (size_t)s_src[row] * D + seg * 4);
        float* p = &s_tile[row * 33 + seg * 4];
        p[0] = v.x; p[1] = v.y; p[2] = v.z; p[3] = v.w;
    }
    __syncthreads();

    const float* Wr = W + (size_t)__builtin_amdgcn_readfirstlane(r) * (D * D);

    float acc[D];
#pragma unroll
    for (int o = 0; o < D; ++o) acc[o] = 0.f;

    if (tid < nE) {
#pragma unroll 4
        for (int d = 0; d < D; ++d) {
            const float hd = s_tile[tid * 33 + d];
#pragma unroll
            for (int o = 0; o < D; ++o)
                acc[o] = fmaf(hd, Wr[d * D + o], acc[o]);
        }
#pragma unroll
        for (int o = 0; o < D; ++o) acc[o] = fmaxf(acc[o], 0.f);
    }
    __syncthreads();

    if (tid < nE) {
#pragma unroll
        for (int o = 0; o < D; ++o) s_tile[tid * 33 + o] = acc[o];
    }
    __syncthreads();

    // scatter rows to dst-sorted msg (one 128B row per 32-lane group) + stats
    float ps = 0.f, pq = 0.f;
    for (int i = tid; i < nE * D; i += TPB) {
        const int row = i >> 5, o = i & 31;
        const float v = s_tile[row * 33 + o];
        msg[(size_t)s_pos[row] * D + o] = v;
        ps += v; pq += v * v;
    }
    s_aux[tid]       = ps;
    s_aux[TPB + tid] = pq;
    __syncthreads();
    if (tid < D) {
        float ss = 0.f, sq = 0.f;
#pragma unroll
        for (int c = 0; c < TPB / D; ++c) {
            ss += s_aux[c * D + tid];
            sq += s_aux[TPB + c * D + tid];
        }
        atomicAdd(&stat_sum[tid], ss);
        atomicAdd(&stat_sq[tid],  sq);
    }
}

// ---------------- R: per-node sequential-stream reduce + BN fold + mean ---
// msg is dst-sorted: node n's messages occupy rows [j0, j1) contiguously.
// Lane o streams column o of those rows — fully coalesced, no indirection.
__global__ void reduce_kernel(const float* __restrict__ msg,
                              const int* __restrict__ node_start,
                              const float* __restrict__ stat_sum,
                              const float* __restrict__ stat_sq,
                              const float* __restrict__ gamma,
                              const float* __restrict__ beta,
                              float invE, float* __restrict__ out, int N)
{
    const int o = threadIdx.x & 31;
    const int n = blockIdx.x * 8 + (threadIdx.x >> 5);
    if (n >= N) return;
    const int j0 = node_start[n], j1 = node_start[n + 1];
    float s = 0.f;
    for (int j = j0; j < j1; ++j)
        s += msg[(size_t)j * D + o];
    const float mu  = stat_sum[o] * invE;
    const float var = fmaxf(stat_sq[o] * invE - mu * mu, 0.f);
    const float is  = rsqrtf(var + EPS);
    const float sc  = gamma[o] * is;
    const float sh  = fmaf(-mu, sc, beta[o]);
    const float c   = (float)(j1 - j0);
    out[(size_t)n * D + o] = fmaf(s, sc, sh * c) / fmaxf(c, 1.0f);
}

extern "C" void kernel_launch(void* const* d_in, const int* in_sizes, int n_in,
                              void* d_out, int out_size, void* d_ws, size_t ws_size,
                              hipStream_t stream)
{
    const float* h     = (const float*)d_in[0];
    const float* W     = (const float*)d_in[1];
    const float* gamma = (const float*)d_in[2];
    const float* beta  = (const float*)d_in[3];
    const int*   src   = (const int*)d_in[4];
    const int*   dst   = (const int*)d_in[5];
    const int*   etype = (const int*)d_in[6];
    float* out = (float*)d_out;

    const int E = in_sizes[4];
    const int N = in_sizes[0] / D;
    const int R = in_sizes[1] / (D * D);
    const int T = R + (E + TPB - 1) / TPB;        // max task count
    const int chunk = (E + NB - 1) / NB;

    // ws layout (4B words):
    // [zeroed: nodeCnt N | stat_sum 32 | stat_sq 32]
    // [node_start N+1 | curD N | rel_start R+1 | n_tasks 1 |
    //  blockHistT R*NB | task_rel T | task_start T | ssrc E | sdst E | msg E*D]
    int*   nodeCnt   = (int*)d_ws;
    float* stat_sum  = (float*)(nodeCnt + N);
    float* stat_sq   = stat_sum + D;
    int*   node_start= (int*)(stat_sq + D);
    int*   curD      = node_start + N + 1;
    int*   rel_start = curD + N;
    int*   n_tasks   = rel_start + R + 1;
    int*   blockHistT= n_tasks + 1;
    int*   task_rel  = blockHistT + R * NB;
    int*   task_start= task_rel + T;
    int*   ssrc      = task_start + T;
    int*   sdst      = ssrc + E;
    float* msg       = (float*)(sdst + E);

    hipMemsetAsync(d_ws, 0, sizeof(int) * (size_t)(N + 2 * D), stream);

    histE_kernel<<<NB, TPB, 0, stream>>>(etype, dst, E, R, chunk, blockHistT, nodeCnt);
    scanAll_kernel<<<1, SCAN_T, 0, stream>>>(blockHistT, R, nodeCnt, N, E,
                                             rel_start, task_rel, task_start, n_tasks,
                                             node_start, curD);
    scatterE_kernel<<<NB, TPB, 0, stream>>>(src, dst, etype, E, R, chunk,
                                            blockHistT, ssrc, sdst);
    rgcn_compute<<<T, TPB, 0, stream>>>(h, W, rel_start, task_rel, task_start,
                                        n_tasks, ssrc, sdst, curD,
                                        msg, stat_sum, stat_sq);
    reduce_kernel<<<(N + 7) / 8, TPB, 0, stream>>>(msg, node_start,
                                                   stat_sum, stat_sq, gamma, beta,
                                                   1.0f / (float)E, out, N);
}